// Round 2
// baseline (186.959 us; speedup 1.0000x reference)
//
#include <hip/hip_runtime.h>

typedef unsigned short u16;
typedef unsigned int u32;

typedef __bf16 bf16x8 __attribute__((ext_vector_type(8)));
typedef float floatx4 __attribute__((ext_vector_type(4)));

// ---- helpers ----------------------------------------------------------------

__device__ __forceinline__ u32 f2bf(float f) {
    // round-to-nearest-even fp32 -> bf16 (bit pattern in low 16)
    u32 u = __builtin_bit_cast(u32, f);
    return (u + 0x7fffu + ((u >> 16) & 1u)) >> 16;
}

__device__ __forceinline__ float quant_w(float x) {
    // WAGE Quantize.W, BITS_W=2: clip to [-0.5,0.5], round to grid step 0.5 (RNE)
    float xc = fminf(fmaxf(x, -0.5f), 0.5f);
    return rintf(xc * 2.0f) * 0.5f;
}

__device__ __forceinline__ u32 cvt_pk_bf16(float lo, float hi) {
    // D[15:0]=bf16(lo), D[31:16]=bf16(hi), RNE (hardware convert; no builtin on gfx950)
    u32 r;
    asm("v_cvt_pk_bf16_f32 %0, %1, %2" : "=v"(r) : "v"(lo), "v"(hi));
    return r;
}

__device__ __forceinline__ void gload_lds16(const u16* g, u16* l) {
    __builtin_amdgcn_global_load_lds(
        (const __attribute__((address_space(1))) void*)g,
        (__attribute__((address_space(3))) void*)l,
        16, 0, 0);
}

// ---- kernel 1: quantize + transpose W[k][n] -> Bt[n][k] bf16 ----------------

__global__ __launch_bounds__(256) void quant_transpose_kernel(const float* __restrict__ W,
                                                              u16* __restrict__ Bt) {
    __shared__ u16 tile[32][33];  // +1 pad: no bank conflicts
    const int KN = 1024;
    int tx = threadIdx.x;  // 0..31
    int ty = threadIdx.y;  // 0..7
    int k0 = blockIdx.y * 32;
    int n0 = blockIdx.x * 32;
#pragma unroll
    for (int i = 0; i < 4; i++) {
        int kl = ty + i * 8;
        float x = W[(k0 + kl) * KN + n0 + tx];
        tile[kl][tx] = (u16)f2bf(quant_w(x));
    }
    __syncthreads();
#pragma unroll
    for (int i = 0; i < 4; i++) {
        int nl = ty + i * 8;
        Bt[(n0 + nl) * KN + k0 + tx] = tile[tx][nl];
    }
}

// ---- kernel 2: fused C[M][N] = cast_bf16(A[M][K]) * Bt[N][K]^T --------------
// 128x128 tile, BK=64 (32 MFMA / barrier). Software-pipelined fusion:
//   B: global_load_lds dwordx4 (pre-swizzled global source, linear LDS).
//   A: fp32 loads for tile t+1 issued in step t (dbuf avA/avB), consumed next
//      step via v_cvt_pk_bf16_f32 + swizzled ds_write_b128.
// Raw s_barrier + counted vmcnt replace __syncthreads so the 8 A-prefetch
// loads stay IN FLIGHT across the barrier (T3/T4-lite — never drain to 0).
//
// Sync ledger (issue order per step: 4 B-DMA, 8 A-prefetch; in-order retire):
//   WAR LDS:  each wave's ds_reads are lgkm-drained before its MFMAs issue,
//             so all LDS reads complete before the wave reaches barrier #1.
//   RAW Bs:   s_waitcnt vmcnt(8) drains exactly the 4 B-DMA (oldest), leaves
//             the 8 A-prefetch outstanding; barrier #2 makes it global.
//   RAW As:   s_waitcnt lgkmcnt(0) (ds_writes) before barrier #2.
//   RAW avX:  compiler-inserted vmcnt before the cvt reads.
//   invariant: LAST iteration still prefetches ((kt+64)&1023 -> tile 0) so the
//             12-op outstanding count backing vmcnt(8) never changes.
//   sched_barrier(0) sandwiches both barriers: no ds op crosses (rule #18).

__global__ __launch_bounds__(256) void gemm_fused_kernel(const float* __restrict__ A32,
                                                         const u16* __restrict__ Bt,
                                                         float* __restrict__ C) {
    const int K = 1024;
    const int N = 1024;

    __shared__ alignas(16) u16 As[128 * 64];  // 16 KB
    __shared__ alignas(16) u16 Bs[128 * 64];  // 16 KB

    const int tid = threadIdx.x;
    const int mbase = blockIdx.x * 128;
    const int nbase = blockIdx.y * 128;
    const int lane = tid & 63;
    const int wv = tid >> 6;
    const int wm = (wv & 1) * 64;
    const int wn = (wv >> 1) * 64;
    const int frow = lane & 15;           // m (or n) index within 16-tile
    const int fkc = lane >> 4;            // k-chunk index within 32-wide k-step (0..3)
    const int rsw = frow & 7;             // XOR bank swizzle key

    floatx4 acc[4][4] = {};

    // B staging: thread t stages chunk q*256+t; row = q*32 + (t>>3),
    // global k-chunk g8 = (t&7) ^ (row&7)  [bank swizzle], LDS linear.
    const int srow = tid >> 3;
    const int g8 = (tid & 7) ^ (srow & 7);
    const u16* Bga[4];
#pragma unroll
    for (int q = 0; q < 4; q++)
        Bga[q] = &Bt[(size_t)(nbase + q * 32 + srow) * K + g8 * 8];

    // A staging: thread t owns row ar = t>>1, k-half ah = t&1 (32 floats/K-step).
    // chunk c -> global chunk gc = ah*4+c -> LDS slot gc ^ (ar&7).
    const int ar = tid >> 1;
    const int ah = tid & 1;
    const float* Ag = &A32[(size_t)(mbase + ar) * K + ah * 32];
    u16* Aw[4];
#pragma unroll
    for (int c = 0; c < 4; c++)
        Aw[c] = &As[ar * 64 + (((ah * 4 + c) ^ (ar & 7)) * 8)];

    float4 avA[8], avB[8];
#pragma unroll
    for (int i = 0; i < 8; i++) avA[i] = *(const float4*)&Ag[4 * i];

    auto step = [&](const float4 (&cur)[8], float4 (&nxt)[8], int kt) {
        __builtin_amdgcn_sched_barrier(0);
        __builtin_amdgcn_s_barrier();      // #1: all waves done reading LDS
        __builtin_amdgcn_sched_barrier(0);

        // B DMA for this tile (4 vmem ops, oldest)
#pragma unroll
        for (int q = 0; q < 4; q++)
            gload_lds16(Bga[q] + kt, &Bs[(q * 256 + tid) * 8]);

        // A prefetch for next tile (8 vmem ops; wrap keeps vmcnt count invariant)
        const int kn = (kt + 64) & (K - 1);
#pragma unroll
        for (int i = 0; i < 8; i++)
            nxt[i] = *(const float4*)&Ag[kn + 4 * i];

        // convert + swizzled LDS write of the tile prefetched LAST step
#pragma unroll
        for (int c = 0; c < 4; c++) {
            uint4 w;
            w.x = cvt_pk_bf16(cur[2 * c].x, cur[2 * c].y);
            w.y = cvt_pk_bf16(cur[2 * c].z, cur[2 * c].w);
            w.z = cvt_pk_bf16(cur[2 * c + 1].x, cur[2 * c + 1].y);
            w.w = cvt_pk_bf16(cur[2 * c + 1].z, cur[2 * c + 1].w);
            *(uint4*)Aw[c] = w;
        }

        asm volatile("s_waitcnt vmcnt(8)" ::: "memory");   // B-DMA done, A in flight
        asm volatile("s_waitcnt lgkmcnt(0)" ::: "memory"); // As ds_writes visible
        __builtin_amdgcn_sched_barrier(0);
        __builtin_amdgcn_s_barrier();      // #2: tile ready for everyone
        __builtin_amdgcn_sched_barrier(0);

#pragma unroll
        for (int s = 0; s < 2; s++) {
            bf16x8 af[4], bf[4];
#pragma unroll
            for (int i = 0; i < 4; i++)
                af[i] = *(const bf16x8*)&As[(wm + i * 16 + frow) * 64 +
                                            (((s * 4 + fkc) ^ rsw) * 8)];
#pragma unroll
            for (int j = 0; j < 4; j++)
                bf[j] = *(const bf16x8*)&Bs[(wn + j * 16 + frow) * 64 +
                                            (((s * 4 + fkc) ^ rsw) * 8)];
#pragma unroll
            for (int i = 0; i < 4; i++)
#pragma unroll
                for (int j = 0; j < 4; j++)
                    acc[i][j] = __builtin_amdgcn_mfma_f32_16x16x32_bf16(
                        af[i], bf[j], acc[i][j], 0, 0, 0);
        }
    };

    for (int kt = 0; kt < K; kt += 128) {
        step(avA, avB, kt);
        step(avB, avA, kt + 64);
    }

    // epilogue: C/D layout col = lane&15, row = (lane>>4)*4 + reg
    const int crow = (lane >> 4) * 4;
    const int ccol = lane & 15;
#pragma unroll
    for (int i = 0; i < 4; i++) {
#pragma unroll
        for (int j = 0; j < 4; j++) {
            float* cp = &C[(size_t)(mbase + wm + i * 16 + crow) * N + nbase + wn + j * 16 + ccol];
#pragma unroll
            for (int r = 0; r < 4; r++) cp[r * N] = acc[i][j][r];
        }
    }
}

// ---- launch -----------------------------------------------------------------

extern "C" void kernel_launch(void* const* d_in, const int* in_sizes, int n_in,
                              void* d_out, int out_size, void* d_ws, size_t ws_size,
                              hipStream_t stream) {
    const float* A = (const float*)d_in[0];   // 16384 x 1024 fp32
    const float* W = (const float*)d_in[1];   // 1024 x 1024 fp32
    float* C = (float*)d_out;                 // 16384 x 1024 fp32

    u16* Btq = (u16*)d_ws;                    // 2 MB quantized transposed weights

    quant_transpose_kernel<<<dim3(32, 32), dim3(32, 8), 0, stream>>>(W, Btq);
    gemm_fused_kernel<<<dim3(128, 8), 256, 0, stream>>>(A, Btq, C);
}

// Round 3
// 150.421 us; speedup vs baseline: 1.2429x; 1.2429x over previous
//
#include <hip/hip_runtime.h>

typedef unsigned short u16;
typedef unsigned int u32;

typedef __bf16 bf16x8 __attribute__((ext_vector_type(8)));
typedef float floatx4 __attribute__((ext_vector_type(4)));

// ---- helpers ----------------------------------------------------------------

__device__ __forceinline__ u32 f2bf(float f) {
    // round-to-nearest-even fp32 -> bf16 (bit pattern in low 16)
    u32 u = __builtin_bit_cast(u32, f);
    return (u + 0x7fffu + ((u >> 16) & 1u)) >> 16;
}

__device__ __forceinline__ float quant_w(float x) {
    // WAGE Quantize.W, BITS_W=2: clip to [-0.5,0.5], round to grid step 0.5 (RNE)
    float xc = fminf(fmaxf(x, -0.5f), 0.5f);
    return rintf(xc * 2.0f) * 0.5f;
}

__device__ __forceinline__ void gload_lds16(const u16* g, u16* l) {
    __builtin_amdgcn_global_load_lds(
        (const __attribute__((address_space(1))) void*)g,
        (__attribute__((address_space(3))) void*)l,
        16, 0, 0);
}

// ---- kernel 1: cast A fp32 -> bf16 (8 floats / thread) ----------------------

__global__ __launch_bounds__(256) void cast_a_kernel(const float4* __restrict__ in,
                                                     uint4* __restrict__ out) {
    int t = blockIdx.x * 256 + threadIdx.x;
    float4 a = in[2 * t];
    float4 b = in[2 * t + 1];
    uint4 o;
    o.x = f2bf(a.x) | (f2bf(a.y) << 16);
    o.y = f2bf(a.z) | (f2bf(a.w) << 16);
    o.z = f2bf(b.x) | (f2bf(b.y) << 16);
    o.w = f2bf(b.z) | (f2bf(b.w) << 16);
    out[t] = o;
}

// ---- kernel 2: quantize + transpose W[k][n] -> Bt[n][k] bf16 ----------------

__global__ __launch_bounds__(256) void quant_transpose_kernel(const float* __restrict__ W,
                                                              u16* __restrict__ Bt) {
    __shared__ u16 tile[32][33];  // +1 pad: no bank conflicts
    const int KN = 1024;
    int tx = threadIdx.x;  // 0..31
    int ty = threadIdx.y;  // 0..7
    int k0 = blockIdx.y * 32;
    int n0 = blockIdx.x * 32;
#pragma unroll
    for (int i = 0; i < 4; i++) {
        int kl = ty + i * 8;
        float x = W[(k0 + kl) * KN + n0 + tx];
        tile[kl][tx] = (u16)f2bf(quant_w(x));
    }
    __syncthreads();
#pragma unroll
    for (int i = 0; i < 4; i++) {
        int nl = ty + i * 8;
        Bt[(n0 + nl) * KN + k0 + tx] = tile[tx][nl];
    }
}

// ---- kernel 3: 256x256 8-phase GEMM  C = A(bf16) * Bt^T ---------------------
// T2+T3+T4+T5 template (guide §5): 512 thr = 8 waves (2M x 4N), per-wave
// output 128x64, BK=64, LDS = 2buf x 2half x 128x64 x {A,B} x bf16 = 128 KB.
// Per tile: 4 phases, each { ds_read subtile | stage 1 half-tile (2 DMA) |
//   barrier | setprio1 + 16 MFMA + setprio0 | barrier }. Counted vmcnt(6)
// once per tile (3 half-tiles / 6 loads stay in flight across barriers).
//
// Stage-unit order per tile tau: u = 4*tau + {0:B0, 1:B1, 2:A0, 3:A1};
// phase P stages u = P+7. Prologue: u0..3, vmcnt(4), u4..6, vmcnt(6), barrier.
// Main tile t: q0 stages (t+1,A1), q1 (t+2,B0), q2 (t+2,B1), q3 (t+2,A0);
// q3 waits vmcnt(6)  [issued-through u=4t+10, drains through u=4t+7 = all of
// tile t+1]. t=14: stage only q0 (u=63), q3 waits vmcnt(0). t=15: none.
//
// WAR ledger (slot <- overwriting stage vs last reader, all in tile t):
//   A[b][0]: read q0(wm0 af0)+q2(wm0 af1)  <- staged t.q3   (q2 barrier first)
//   A[b][1]: read q0/q2 by wm1            <- staged t.q0 targets buf b^1: safe
//   B[b][0]: read q0                      <- staged t.q1
//   B[b][1]: read q1                      <- staged t.q2
// RAW: tile t+1 fully landed by t.q3's vmcnt(6) + closing barrier.

__global__ __launch_bounds__(512, 2) void gemm_8phase_kernel(const u16* __restrict__ A,
                                                             const u16* __restrict__ Bt,
                                                             float* __restrict__ C) {
    const int K = 1024;
    const int N = 1024;

    __shared__ alignas(16) u16 As[2 * 2 * 128 * 64];  // 64 KB
    __shared__ alignas(16) u16 Bs[2 * 2 * 128 * 64];  // 64 KB

    const int tid = threadIdx.x;
    const int lane = tid & 63;
    const int wid = tid >> 6;     // 0..7
    const int wm = wid >> 2;      // 0..1  (M half: 128 rows)
    const int wn = wid & 3;       // 0..3  (N quarter: 64 cols)
    const int frow = lane & 15;
    const int fkc = lane >> 4;    // k-chunk 0..3
    const int rsw = frow & 7;     // XOR bank-swizzle key
    const int mbase = blockIdx.x * 256;
    const int nbase = blockIdx.y * 256;

    // staging thread map: row sr (+0/64), swizzled global k-chunk gc
    const int sr = tid >> 3;              // 0..63
    const int gc = (tid & 7) ^ (sr & 7);

    const u16* Abase = &A[(size_t)(mbase + sr) * K + gc * 8];
    const u16* Bbase = &Bt[(size_t)(nbase + sr) * K + gc * 8];

    floatx4 acc[8][4] = {};

    // stage unit q of tile tau. q: 0=B-half0, 1=B-half1, 2=A-half0, 3=A-half1
    auto stage = [&](int tau, int q) {
        const int hf = q & 1;
        const int isA = q >> 1;
        const u16* gb = isA ? Abase : Bbase;
        u16* lb = isA ? As : Bs;
        const size_t goff = (size_t)(hf * 128) * K + (size_t)tau * 64;
        u16* dst = &lb[(((tau & 1) * 2 + hf) * 8192) + tid * 8];
        gload_lds16(gb + goff, dst);
        gload_lds16(gb + goff + (size_t)64 * K, dst + 4096);
    };

#define BAR_PRE()                              \
    __builtin_amdgcn_sched_barrier(0);         \
    __builtin_amdgcn_s_barrier();              \
    __builtin_amdgcn_sched_barrier(0);         \
    __builtin_amdgcn_s_setprio(1)
#define BAR_POST()                             \
    __builtin_amdgcn_s_setprio(0);             \
    __builtin_amdgcn_sched_barrier(0);         \
    __builtin_amdgcn_s_barrier();              \
    __builtin_amdgcn_sched_barrier(0)

    // ---- prologue: tile0 {B0,B1,A0,A1}, vmcnt(4), tile1 {B0,B1,A0}, vmcnt(6)
    stage(0, 0); stage(0, 1); stage(0, 2); stage(0, 3);
    asm volatile("s_waitcnt vmcnt(4)" ::: "memory");
    stage(1, 0); stage(1, 1); stage(1, 2);
    asm volatile("s_waitcnt vmcnt(6)" ::: "memory");
    __builtin_amdgcn_sched_barrier(0);
    __builtin_amdgcn_s_barrier();
    __builtin_amdgcn_sched_barrier(0);

    for (int t = 0; t < 16; t++) {
        const int b = t & 1;
        const int a_sl = ((b * 2 + wm) * 128) * 64;            // wave's A slot base
        const int b_sl = ((b * 2 + (wn >> 1)) * 128) * 64;     // wave's B slot base
        const int lrb0 = (wn & 1) * 64;                        // B local-row base

        bf16x8 af0[4][2], af1[4][2], bf0[2][2], bf1[2][2];

        // ---------- phase q0: reads A-mh0 (8) + B-nh0 (4); MFMA (0,0) ----------
#pragma unroll
        for (int mf = 0; mf < 4; mf++)
#pragma unroll
            for (int s = 0; s < 2; s++)
                af0[mf][s] = *(const bf16x8*)&As[a_sl + (mf * 16 + frow) * 64 +
                                                (((s * 4 + fkc) ^ rsw) * 8)];
#pragma unroll
        for (int nf = 0; nf < 2; nf++)
#pragma unroll
            for (int s = 0; s < 2; s++)
                bf0[nf][s] = *(const bf16x8*)&Bs[b_sl + (lrb0 + nf * 16 + frow) * 64 +
                                                 (((s * 4 + fkc) ^ rsw) * 8)];
        if (t < 15) stage(t + 1, 3);
        BAR_PRE();
#pragma unroll
        for (int mf = 0; mf < 4; mf++)
#pragma unroll
            for (int nf = 0; nf < 2; nf++)
#pragma unroll
                for (int s = 0; s < 2; s++)
                    acc[mf][nf] = __builtin_amdgcn_mfma_f32_16x16x32_bf16(
                        af0[mf][s], bf0[nf][s], acc[mf][nf], 0, 0, 0);
        BAR_POST();

        // ---------- phase q1: reads B-nh1 (4); MFMA (0,1) ----------
#pragma unroll
        for (int nf = 0; nf < 2; nf++)
#pragma unroll
            for (int s = 0; s < 2; s++)
                bf1[nf][s] = *(const bf16x8*)&Bs[b_sl + (lrb0 + 32 + nf * 16 + frow) * 64 +
                                                 (((s * 4 + fkc) ^ rsw) * 8)];
        if (t < 14) stage(t + 2, 0);
        BAR_PRE();
#pragma unroll
        for (int mf = 0; mf < 4; mf++)
#pragma unroll
            for (int nf = 0; nf < 2; nf++)
#pragma unroll
                for (int s = 0; s < 2; s++)
                    acc[mf][2 + nf] = __builtin_amdgcn_mfma_f32_16x16x32_bf16(
                        af0[mf][s], bf1[nf][s], acc[mf][2 + nf], 0, 0, 0);
        BAR_POST();

        // ---------- phase q2: reads A-mh1 (8); MFMA (1,0) ----------
#pragma unroll
        for (int mf = 0; mf < 4; mf++)
#pragma unroll
            for (int s = 0; s < 2; s++)
                af1[mf][s] = *(const bf16x8*)&As[a_sl + (64 + mf * 16 + frow) * 64 +
                                                (((s * 4 + fkc) ^ rsw) * 8)];
        if (t < 14) stage(t + 2, 1);
        BAR_PRE();
#pragma unroll
        for (int mf = 0; mf < 4; mf++)
#pragma unroll
            for (int nf = 0; nf < 2; nf++)
#pragma unroll
                for (int s = 0; s < 2; s++)
                    acc[4 + mf][nf] = __builtin_amdgcn_mfma_f32_16x16x32_bf16(
                        af1[mf][s], bf0[nf][s], acc[4 + mf][nf], 0, 0, 0);
        BAR_POST();

        // ---------- phase q3: no reads; tile-ready wait; MFMA (1,1) ----------
        if (t < 14) stage(t + 2, 2);
        if (t < 14) {
            asm volatile("s_waitcnt vmcnt(6)" ::: "memory");
        } else if (t == 14) {
            asm volatile("s_waitcnt vmcnt(0)" ::: "memory");
        }
        BAR_PRE();
#pragma unroll
        for (int mf = 0; mf < 4; mf++)
#pragma unroll
            for (int nf = 0; nf < 2; nf++)
#pragma unroll
                for (int s = 0; s < 2; s++)
                    acc[4 + mf][2 + nf] = __builtin_amdgcn_mfma_f32_16x16x32_bf16(
                        af1[mf][s], bf1[nf][s], acc[4 + mf][2 + nf], 0, 0, 0);
        BAR_POST();
    }

#undef BAR_PRE
#undef BAR_POST

    // epilogue: C/D layout col = lane&15, row = (lane>>4)*4 + reg
    const int crow = (lane >> 4) * 4;
    const int ccol = lane & 15;
#pragma unroll
    for (int i = 0; i < 8; i++) {
#pragma unroll
        for (int j = 0; j < 4; j++) {
            float* cp = &C[(size_t)(mbase + wm * 128 + i * 16 + crow) * N +
                           nbase + wn * 64 + j * 16 + ccol];
#pragma unroll
            for (int r = 0; r < 4; r++) cp[r * N] = acc[i][j][r];
        }
    }
}

// ---- launch -----------------------------------------------------------------

extern "C" void kernel_launch(void* const* d_in, const int* in_sizes, int n_in,
                              void* d_out, int out_size, void* d_ws, size_t ws_size,
                              hipStream_t stream) {
    const float* A = (const float*)d_in[0];   // 16384 x 1024 fp32
    const float* W = (const float*)d_in[1];   // 1024 x 1024 fp32
    float* C = (float*)d_out;                 // 16384 x 1024 fp32

    u16* Abf = (u16*)d_ws;                                   // 32 MB bf16 A
    u16* Btq = (u16*)((char*)d_ws + (size_t)33554432);       // 2 MB quantized W^T

    cast_a_kernel<<<8192, 256, 0, stream>>>((const float4*)A, (uint4*)Abf);
    quant_transpose_kernel<<<dim3(32, 32), dim3(32, 8), 0, stream>>>(W, Btq);
    gemm_8phase_kernel<<<dim3(64, 4), 512, 0, stream>>>(Abf, Btq, C);
}

// Round 5
// 145.198 us; speedup vs baseline: 1.2876x; 1.0360x over previous
//
#include <hip/hip_runtime.h>

typedef unsigned short u16;
typedef unsigned int u32;

typedef __bf16 bf16x8 __attribute__((ext_vector_type(8)));
typedef float floatx4 __attribute__((ext_vector_type(4)));

// ---- helpers ----------------------------------------------------------------

__device__ __forceinline__ u32 f2bf(float f) {
    // round-to-nearest-even fp32 -> bf16 (bit pattern in low 16)
    u32 u = __builtin_bit_cast(u32, f);
    return (u + 0x7fffu + ((u >> 16) & 1u)) >> 16;
}

__device__ __forceinline__ float quant_w(float x) {
    // WAGE Quantize.W, BITS_W=2: clip to [-0.5,0.5], round to grid step 0.5 (RNE)
    float xc = fminf(fmaxf(x, -0.5f), 0.5f);
    return rintf(xc * 2.0f) * 0.5f;
}

__device__ __forceinline__ void gload_lds16(const u16* g, u16* l) {
    __builtin_amdgcn_global_load_lds(
        (const __attribute__((address_space(1))) void*)g,
        (__attribute__((address_space(3))) void*)l,
        16, 0, 0);
}

// ---- kernel 1: cast A fp32 -> bf16 (8 floats / thread) ----------------------

__global__ __launch_bounds__(256) void cast_a_kernel(const float4* __restrict__ in,
                                                     uint4* __restrict__ out) {
    int t = blockIdx.x * 256 + threadIdx.x;
    float4 a = in[2 * t];
    float4 b = in[2 * t + 1];
    uint4 o;
    o.x = f2bf(a.x) | (f2bf(a.y) << 16);
    o.y = f2bf(a.z) | (f2bf(a.w) << 16);
    o.z = f2bf(b.x) | (f2bf(b.y) << 16);
    o.w = f2bf(b.z) | (f2bf(b.w) << 16);
    out[t] = o;
}

// ---- kernel 2: quantize + transpose W[k][n] -> Bt[n][k] bf16 ----------------

__global__ __launch_bounds__(256) void quant_transpose_kernel(const float* __restrict__ W,
                                                              u16* __restrict__ Bt) {
    __shared__ u16 tile[32][33];  // +1 pad: no bank conflicts
    const int KN = 1024;
    int tx = threadIdx.x;  // 0..31
    int ty = threadIdx.y;  // 0..7
    int k0 = blockIdx.y * 32;
    int n0 = blockIdx.x * 32;
#pragma unroll
    for (int i = 0; i < 4; i++) {
        int kl = ty + i * 8;
        float x = W[(k0 + kl) * KN + n0 + tx];
        tile[kl][tx] = (u16)f2bf(quant_w(x));
    }
    __syncthreads();
#pragma unroll
    for (int i = 0; i < 4; i++) {
        int nl = ty + i * 8;
        Bt[(n0 + nl) * KN + k0 + tx] = tile[tx][nl];
    }
}

// ---- kernel 3: 256x256 4-region pipelined GEMM  C = A(bf16) * Bt^T ----------
// 512 thr = 8 waves (2M x 4N), per-wave 128x64 out, BK=64, LDS 128 KB (2 dbuf).
// LDS slots are per (buffer, M-half or N-half): slot = 128 rows x 64 cols.
// A wave's af0/af1 are row-halves of ONE A slot; bf0/bf1 of ONE B slot.
//
// Region schedule (1 barrier each; MFMA cluster consumes fragments read in a
// PRIOR region, ds_reads/stages overlap the matrix pipe):
//   G0: M3(t-1)[af1 x bf1] || read af0,bf0(t) (12)            | lgkm, bar
//   G1: M0(t)  [af0 x bf0] || read af1(t)     (8)             | lgkm, bar
//   G2: M1(t)  [af1 x bf0] || read bf1(t) (4) | stage A0,A1(t+2) | lgkm, bar
//   G3: M2(t)  [af0 x bf1] || stage B0,B1(t+2) ; vmcnt(8)     | bar
//
// WAR (slot last-read -> overwriting stage, all chip-wide via lgkm+barrier):
//   A slots: last read G1 (af1) -> staged G2.  B slots: last read G2 (bf1)
//   -> staged G3.  No region reads and stages the same array: zero
//   same-region aliasing (R4's bug: A-stage in G1 raced G2's af1 reads).
// RAW (counted vmcnt, in-order retire; 8 loads/tile, 4@G2 + 4@G3 -> t+2):
//   at G3(t<=13): queue = [t+1's 8, t+2's 8]; vmcnt(8) drains exactly t+1
//   before G0(t+1) reads it; t=14: vmcnt(0) (queue = t15's 8); never 0 before.
// Per-acc MFMA order identical to the verified R3 kernel -> bitwise-equal C.

__global__ __launch_bounds__(512, 2) void gemm_4region_kernel(const u16* __restrict__ A,
                                                              const u16* __restrict__ Bt,
                                                              float* __restrict__ C) {
    const int K = 1024;
    const int N = 1024;

    __shared__ alignas(16) u16 As[2 * 2 * 128 * 64];  // 64 KB
    __shared__ alignas(16) u16 Bs[2 * 2 * 128 * 64];  // 64 KB

    const int tid = threadIdx.x;
    const int lane = tid & 63;
    const int wid = tid >> 6;
    const int wm = wid >> 2;      // M half (128 rows)
    const int wn = wid & 3;       // N quarter (64 cols)
    const int frow = lane & 15;
    const int fkc = lane >> 4;
    const int rsw = frow & 7;
    const int mbase = blockIdx.x * 256;
    const int nbase = blockIdx.y * 256;

    const int sr = tid >> 3;
    const int gc = (tid & 7) ^ (sr & 7);

    const u16* Abase = &A[(size_t)(mbase + sr) * K + gc * 8];
    const u16* Bbase = &Bt[(size_t)(nbase + sr) * K + gc * 8];

    floatx4 acc[8][4] = {};
    bf16x8 af0[4][2], af1[4][2], bf0[2][2], bf1[2][2];

    // stage unit q of tile tau. q: 0=B-half0, 1=B-half1, 2=A-half0, 3=A-half1
    auto stage = [&](int tau, int q) {
        const int hf = q & 1;
        const int isA = q >> 1;
        const u16* gb = isA ? Abase : Bbase;
        u16* lb = isA ? As : Bs;
        const size_t goff = (size_t)(hf * 128) * K + (size_t)tau * 64;
        u16* dst = &lb[(((tau & 1) * 2 + hf) * 8192) + tid * 8];
        gload_lds16(gb + goff, dst);
        gload_lds16(gb + goff + (size_t)64 * K, dst + 4096);
    };

#define LGKM0() asm volatile("s_waitcnt lgkmcnt(0)" ::: "memory")
#define VMC(n)  asm volatile("s_waitcnt vmcnt(" #n ")" ::: "memory")
#define BAR()                          \
    __builtin_amdgcn_sched_barrier(0); \
    __builtin_amdgcn_s_barrier();      \
    __builtin_amdgcn_sched_barrier(0)

#define READ_AF0(b)                                                                  \
    _Pragma("unroll") for (int mf = 0; mf < 4; mf++)                                 \
        _Pragma("unroll") for (int s = 0; s < 2; s++)                                \
            af0[mf][s] = *(const bf16x8*)&As[(((b)*2 + wm) * 128 + mf * 16 + frow) * 64 + \
                                             (((s * 4 + fkc) ^ rsw) * 8)]
#define READ_AF1(b)                                                                  \
    _Pragma("unroll") for (int mf = 0; mf < 4; mf++)                                 \
        _Pragma("unroll") for (int s = 0; s < 2; s++)                                \
            af1[mf][s] = *(const bf16x8*)&As[(((b)*2 + wm) * 128 + 64 + mf * 16 + frow) * 64 + \
                                             (((s * 4 + fkc) ^ rsw) * 8)]
#define READ_BF0(b)                                                                  \
    _Pragma("unroll") for (int nf = 0; nf < 2; nf++)                                 \
        _Pragma("unroll") for (int s = 0; s < 2; s++)                                \
            bf0[nf][s] = *(const bf16x8*)&Bs[(((b)*2 + (wn >> 1)) * 128 + (wn & 1) * 64 + nf * 16 + frow) * 64 + \
                                             (((s * 4 + fkc) ^ rsw) * 8)]
#define READ_BF1(b)                                                                  \
    _Pragma("unroll") for (int nf = 0; nf < 2; nf++)                                 \
        _Pragma("unroll") for (int s = 0; s < 2; s++)                                \
            bf1[nf][s] = *(const bf16x8*)&Bs[(((b)*2 + (wn >> 1)) * 128 + (wn & 1) * 64 + 32 + nf * 16 + frow) * 64 + \
                                             (((s * 4 + fkc) ^ rsw) * 8)]
#define MFMA_CL(af, bf, mo, no)                                                      \
    __builtin_amdgcn_s_setprio(1);                                                   \
    _Pragma("unroll") for (int mf = 0; mf < 4; mf++)                                 \
        _Pragma("unroll") for (int nf = 0; nf < 2; nf++)                             \
            _Pragma("unroll") for (int s = 0; s < 2; s++)                            \
                acc[(mo) + mf][(no) + nf] = __builtin_amdgcn_mfma_f32_16x16x32_bf16( \
                    af[mf][s], bf[nf][s], acc[(mo) + mf][(no) + nf], 0, 0, 0);       \
    __builtin_amdgcn_s_setprio(0)

    // ---- prologue: stage tiles 0 and 1 (16 vmem ops), land tile 0 ----
    stage(0, 0); stage(0, 1); stage(0, 2); stage(0, 3);
    stage(1, 0); stage(1, 1); stage(1, 2); stage(1, 3);
    VMC(8);
    BAR();

    for (int t = 0; t < 16; t++) {
        const int b = t & 1;

        // ---- G0: M3(t-1) || read af0,bf0(t) ----
        if (t > 0) { MFMA_CL(af1, bf1, 4, 2); }
        READ_AF0(b);
        READ_BF0(b);
        LGKM0();
        BAR();

        // ---- G1: M0(t) || read af1(t) ----
        MFMA_CL(af0, bf0, 0, 0);
        READ_AF1(b);
        LGKM0();
        BAR();

        // ---- G2: M1(t) || read bf1(t) | stage A0,A1 -> t+2 ----
        MFMA_CL(af1, bf0, 4, 0);
        READ_BF1(b);
        if (t <= 13) { stage(t + 2, 2); stage(t + 2, 3); }
        LGKM0();
        BAR();

        // ---- G3: M2(t) || stage B0,B1 -> t+2 ; counted vmcnt ----
        MFMA_CL(af0, bf1, 0, 2);
        if (t <= 13) {
            stage(t + 2, 0); stage(t + 2, 1);
            VMC(8);
        } else if (t == 14) {
            VMC(0);
        }
        BAR();
    }

    // ---- epilogue MFMA: M3(15) ----
    MFMA_CL(af1, bf1, 4, 2);

#undef LGKM0
#undef VMC
#undef BAR
#undef READ_AF0
#undef READ_AF1
#undef READ_BF0
#undef READ_BF1
#undef MFMA_CL

    // epilogue: C/D layout col = lane&15, row = (lane>>4)*4 + reg
    const int crow = (lane >> 4) * 4;
    const int ccol = lane & 15;
#pragma unroll
    for (int i = 0; i < 8; i++) {
#pragma unroll
        for (int j = 0; j < 4; j++) {
            float* cp = &C[(size_t)(mbase + wm * 128 + i * 16 + crow) * N +
                           nbase + wn * 64 + j * 16 + ccol];
#pragma unroll
            for (int r = 0; r < 4; r++) cp[r * N] = acc[i][j][r];
        }
    }
}

// ---- launch -----------------------------------------------------------------

extern "C" void kernel_launch(void* const* d_in, const int* in_sizes, int n_in,
                              void* d_out, int out_size, void* d_ws, size_t ws_size,
                              hipStream_t stream) {
    const float* A = (const float*)d_in[0];   // 16384 x 1024 fp32
    const float* W = (const float*)d_in[1];   // 1024 x 1024 fp32
    float* C = (float*)d_out;                 // 16384 x 1024 fp32

    u16* Abf = (u16*)d_ws;                                   // 32 MB bf16 A
    u16* Btq = (u16*)((char*)d_ws + (size_t)33554432);       // 2 MB quantized W^T

    cast_a_kernel<<<8192, 256, 0, stream>>>((const float4*)A, (uint4*)Abf);
    quant_transpose_kernel<<<dim3(32, 32), dim3(32, 8), 0, stream>>>(W, Btq);
    gemm_4region_kernel<<<dim3(64, 4), 512, 0, stream>>>(Abf, Btq, C);
}